// Round 5
// baseline (786.249 us; speedup 1.0000x reference)
//
#include <hip/hip_runtime.h>

#define VC 1600
#define EPSF 1e-5f

// ws layout (float offsets)
#define WS_MASKJ  0
#define WS_WPACK  1600
#define WS_DWPACK 5696
#define WS_ABY    9792             // fallback path
#define WS_ABR    16192            // fallback path
#define WS_COLSUM 16448
#define WS_QY     18048            // 3328 floats: [0,3200)=y (v,d) sumsq, [3200,3328)=res d sumsq
#define WS_CFL    24576            // float4[12800]: fused coeffs (ay, by+br, ar, 0) indexed d*100+L
#define WS_YR_SH  153600           // SHORT offset: interleaved (y,r) bf16, [chunk][d][L][2]
#define WS_NEED_BYTES 216628736ULL

typedef __attribute__((ext_vector_type(8))) short s16x8;
typedef __attribute__((ext_vector_type(4))) short s16x4;
typedef __attribute__((ext_vector_type(4))) float f32x4;

__device__ __forceinline__ short f2bf(float f) {
  unsigned u = __builtin_bit_cast(unsigned, f);
  u += 0x7fffu + ((u >> 16) & 1u);
  return (short)(u >> 16);
}
__device__ __forceinline__ float bf2f(short s) {
  unsigned u = ((unsigned)(unsigned short)s) << 16;
  return __builtin_bit_cast(float, u);
}

// stage one float4: raw (contiguous) + masked scatter to gathered position.
__device__ __forceinline__ void stage_elem(int j, int base, int vstr, float4 xv,
                                           const float* mj, short* s_raw, short* s_xm) {
  int u = j >> 6, c = j & 63;
  s16x4 pk; pk[0]=f2bf(xv.x); pk[1]=f2bf(xv.y); pk[2]=f2bf(xv.z); pk[3]=f2bf(xv.w);
  *(s16x4*)(s_raw + (base + u*vstr)*72 + c) = pk;
  int v0 = (u - c + 75) % 25;
  float xa[4] = {xv.x, xv.y, xv.z, xv.w};
#pragma unroll
  for (int e = 0; e < 4; e++) {
    int ve = v0 - e; if (ve < 0) ve += 25;
    s_xm[(base + ve*vstr)*72 + c + e] = f2bf(xa[e] * mj[e]);
  }
}

// ---------------- init ----------------
__global__ void k_init(const float* __restrict__ fm, const float* __restrict__ W,
                       const float* __restrict__ dw, float* __restrict__ ws) {
  int g = blockIdx.x * 256 + threadIdx.x;
  if (g < VC) {
    int c = g & 63, jv = g >> 6;
    int v = (jv - c + 75) % 25;
    ws[WS_MASKJ + g] = tanhf(fm[v * 64 + c]) + 1.0f;
    ws[WS_COLSUM + g] = 0.0f;
  }
  if (g < 3328) ws[WS_QY + g] = 0.0f;
  if (g >= 3328 && g < 4352) {
    int idx = g - 3328;
    int frag = idx >> 6, lane = idx & 63;
    int nt = frag >> 1, k = frag & 1, q = lane >> 4, l = lane & 15;
    s16x8 pk;
#pragma unroll
    for (int j = 0; j < 8; j++) {
      int c = k * 32 + q * 8 + j;
      pk[j] = f2bf(W[c * 128 + nt * 16 + l]);
    }
    ((s16x8*)(ws + WS_WPACK))[idx] = pk;
  }
  if (g >= 4352 && g < 5376) {
    int idx = g - 4352;
    int frag = idx >> 6, lane = idx & 63;
    int nt = frag >> 1, k = frag & 1, q = lane >> 4, l = lane & 15;
    s16x8 pk;
#pragma unroll
    for (int j = 0; j < 8; j++) {
      int c = k * 32 + q * 8 + j;
      pk[j] = f2bf(dw[(nt * 16 + l) * 64 + c]);
    }
    ((s16x8*)(ws + WS_DWPACK))[idx] = pk;
  }
}

// ---------------- pass 1: stats + in-LDS unscramble + linear flush ----------------
// 4-row chunks (vstr=4): slot = r + v*4, 100 slots (+12 garbage pad, guarded).
// Phases per chunk: stage -> bar -> MFMA (stats + transposed y/r into regs) -> bar
//   -> scatter into s_mem as [d][L=r*25+vo][2] (shift applied; y/r interleaved)
//   -> bar -> linear flush to global. LDS union: stage/MFMA use 32.3KB, scatter 51.2KB.
__launch_bounds__(256, 2)
__global__ void k_stats(const float* __restrict__ x0, float* __restrict__ ws, int do_store) {
  __shared__ __align__(16) short s_mem[25600];   // 51200 B union
  short* s_raw = s_mem;                          // [0, 8064)
  short* s_xm  = s_mem + 8064;                   // [8064, 16128)
  int tid = threadIdx.x;
  int wave = tid >> 6, lane = tid & 63, quad = lane >> 4, l15 = lane & 15;
  const s16x8* wpack = (const s16x8*)(ws + WS_WPACK);
  const s16x8* dwpack = (const s16x8*)(ws + WS_DWPACK);

  int nt0 = wave * 2;
  s16x8 bw[2][2], bd[2][2];
#pragma unroll
  for (int a = 0; a < 2; a++) {
    int nt = nt0 + a;
    bw[a][0] = wpack[(nt * 2 + 0) * 64 + lane];
    bw[a][1] = wpack[(nt * 2 + 1) * 64 + lane];
    bd[a][0] = dwpack[(nt * 2 + 0) * 64 + lane];
    bd[a][1] = dwpack[(nt * 2 + 1) * 64 + lane];
  }
  float mj0[4], mj1[4];
  {
    float4 m4 = *(const float4*)(ws + WS_MASKJ + tid * 4);
    mj0[0]=m4.x; mj0[1]=m4.y; mj0[2]=m4.z; mj0[3]=m4.w;
  }
  if (tid < 144) {
    float4 m4 = *(const float4*)(ws + WS_MASKJ + 1024 + tid * 4);
    mj1[0]=m4.x; mj1[1]=m4.y; mj1[2]=m4.z; mj1[3]=m4.w;
  }
  float cs[8] = {0,0,0,0,0,0,0,0};
  float rq0 = 0.f, rq1 = 0.f;
  float qy[7][2];
#pragma unroll
  for (int i = 0; i < 7; i++) { qy[i][0] = 0.f; qy[i][1] = 0.f; }
  s16x4 kyv[7][2], krv[7][2];

  for (int chunk = 0; chunk < 8; chunk++) {
    int n0 = blockIdx.x * 32 + chunk * 4;
    int cg = blockIdx.x * 8 + chunk;
    __syncthreads();   // previous flush reads done before stage overwrites
    for (int r = 0; r < 4; r++) {
      const float* rowp = x0 + (size_t)(n0 + r) * VC;
      float4 xv = *(const float4*)(rowp + tid * 4);
      cs[0]+=xv.x; cs[1]+=xv.y; cs[2]+=xv.z; cs[3]+=xv.w;
      stage_elem(tid * 4, r, 4, xv, mj0, s_raw, s_xm);
      if (tid < 144) {
        float4 xw = *(const float4*)(rowp + 1024 + tid * 4);
        cs[4]+=xw.x; cs[5]+=xw.y; cs[6]+=xw.z; cs[7]+=xw.w;
        stage_elem(1024 + tid * 4, r, 4, xw, mj1, s_raw, s_xm);
      }
    }
    __syncthreads();
#pragma unroll
    for (int vp = 0; vp < 7; vp++) {
      int rb = vp * 16;
      const short* px = s_xm + (rb + l15) * 72 + quad * 8;
      const short* pr = s_raw + (rb + l15) * 72 + quad * 8;
      s16x8 a0 = *(const s16x8*)px;
      s16x8 a1 = *(const s16x8*)(px + 32);
      s16x8 r0 = *(const s16x8*)pr;
      s16x8 r1 = *(const s16x8*)(pr + 32);
#pragma unroll
      for (int a = 0; a < 2; a++) {
        f32x4 acc = {0.f, 0.f, 0.f, 0.f};
        acc = __builtin_amdgcn_mfma_f32_16x16x32_bf16(a0, bw[a][0], acc, 0, 0, 0);
        acc = __builtin_amdgcn_mfma_f32_16x16x32_bf16(a1, bw[a][1], acc, 0, 0, 0);
        qy[vp][a] += acc[0]*acc[0] + acc[1]*acc[1] + acc[2]*acc[2] + acc[3]*acc[3];
        f32x4 rc = {0.f, 0.f, 0.f, 0.f};
        rc = __builtin_amdgcn_mfma_f32_16x16x32_bf16(r0, bd[a][0], rc, 0, 0, 0);
        rc = __builtin_amdgcn_mfma_f32_16x16x32_bf16(r1, bd[a][1], rc, 0, 0, 0);
        float t2 = rc[0]*rc[0] + rc[1]*rc[1] + rc[2]*rc[2] + rc[3]*rc[3];
        // pad slots 100..111 hold garbage (no zeroing): only quad 0 of vp==6 is valid
        if (vp < 6 || quad == 0) { if (a == 0) rq0 += t2; else rq1 += t2; }
      }
      if (do_store) {
        // transposed MFMAs (swap A/B): lane holds 4 consecutive d for slot = rb + l15
#pragma unroll
        for (int aa = 0; aa < 2; aa++) {
          f32x4 tY = {0.f, 0.f, 0.f, 0.f};
          tY = __builtin_amdgcn_mfma_f32_16x16x32_bf16(bw[aa][0], a0, tY, 0, 0, 0);
          tY = __builtin_amdgcn_mfma_f32_16x16x32_bf16(bw[aa][1], a1, tY, 0, 0, 0);
          f32x4 tR = {0.f, 0.f, 0.f, 0.f};
          tR = __builtin_amdgcn_mfma_f32_16x16x32_bf16(bd[aa][0], r0, tR, 0, 0, 0);
          tR = __builtin_amdgcn_mfma_f32_16x16x32_bf16(bd[aa][1], r1, tR, 0, 0, 0);
          s16x4 ky, kr;
#pragma unroll
          for (int e = 0; e < 4; e++) { ky[e] = f2bf(tY[e]); kr[e] = f2bf(tR[e]); }
          kyv[vp][aa] = ky; krv[vp][aa] = kr;
        }
      }
    }
    __syncthreads();   // all MFMA reads of s_raw/s_xm done; union becomes yr buffer
    if (do_store) {
#pragma unroll
      for (int vp = 0; vp < 7; vp++) {
        if (vp < 6 || l15 < 4) {
          int slot = vp * 16 + l15;
          int v = slot >> 2, r = slot & 3;
          int Lr = r * 25 + v;
#pragma unroll
          for (int aa = 0; aa < 2; aa++) {
            int d0 = (nt0 + aa) * 16 + quad * 4;
            int d25 = d0 % 25;
#pragma unroll
            for (int e = 0; e < 4; e++) {
              int d = d0 + e;
              int de = d25 + e; if (de >= 25) de -= 25;
              int vo = v + de; if (vo >= 25) vo -= 25;
              s_mem[(d * 100 + r * 25 + vo) * 2]     = kyv[vp][aa][e];  // y at shifted pos
              s_mem[(d * 100 + Lr) * 2 + 1]          = krv[vp][aa][e];  // r unshifted
            }
          }
        }
      }
    }
    __syncthreads();
    if (do_store) {
      short* gyr = (short*)ws + WS_YR_SH + (size_t)cg * 25600;
      for (int t = tid; t < 3200; t += 256)
        *(s16x8*)(gyr + t * 8) = *(const s16x8*)(s_mem + t * 8);
    }
  }
  // accumulate stats straight into global accumulators (zeroed by k_init each launch)
  rq0 += __shfl_xor(rq0, 16); rq0 += __shfl_xor(rq0, 32);
  rq1 += __shfl_xor(rq1, 16); rq1 += __shfl_xor(rq1, 32);
  if (quad == 0) {
    atomicAdd(ws + WS_QY + 3200 + nt0 * 16 + l15, rq0);
    atomicAdd(ws + WS_QY + 3200 + (nt0 + 1) * 16 + l15, rq1);
  }
#pragma unroll
  for (int vp = 0; vp < 7; vp++) {
    int vq = vp * 4 + quad;
    if (vq < 25) {
      atomicAdd(ws + WS_QY + vq * 128 + nt0 * 16 + l15, qy[vp][0]);
      atomicAdd(ws + WS_QY + vq * 128 + (nt0 + 1) * 16 + l15, qy[vp][1]);
    }
  }
#pragma unroll
  for (int e = 0; e < 4; e++) atomicAdd(ws + WS_COLSUM + tid * 4 + e, cs[e]);
  if (tid < 144) {
#pragma unroll
    for (int e = 0; e < 4; e++) atomicAdd(ws + WS_COLSUM + 1024 + tid * 4 + e, cs[4 + e]);
  }
}

// ---------------- reduce (big path): fused coeff table CFL[d*100+L] ----------------
__global__ void k_reduce_big(const float* __restrict__ gamma, const float* __restrict__ beta,
                             const float* __restrict__ dgamma, const float* __restrict__ dbeta,
                             const float* __restrict__ W, const float* __restrict__ dw,
                             float* __restrict__ ws) {
  __shared__ float s_cm[1600];
  __shared__ float s_cs[64];
  int tid = threadIdx.x;
  for (int t = tid; t < 1600; t += 128) s_cm[t] = ws[WS_COLSUM + t] * ws[WS_MASKJ + t];
  if (tid < 64) {
    float s = 0.f;
#pragma unroll
    for (int v2 = 0; v2 < 25; v2++) s += ws[WS_COLSUM + v2 * 64 + tid];
    s_cs[tid] = s;
  }
  __syncthreads();
  int v = blockIdx.x, d = tid;
  // y path
  float q = ws[WS_QY + v * 128 + d];
  float m = 0.f;
  int p = v * 64;
#pragma unroll 8
  for (int c = 0; c < 64; c++) { m += s_cm[p] * W[c * 128 + d]; p += 65; if (p >= VC) p -= VC; }
  m *= (1.0f / 16384.0f);
  float var = q * (1.0f / 16384.0f) - m * m;
  int d25 = d % 25;
  int vo = v + d25; if (vo >= 25) vo -= 25;
  int jg = vo * 128 + d;
  float ay = gamma[jg] * rsqrtf(var + EPSF);
  float by = beta[jg] - m * ay;
  // res path (redundant across blocks; cheap)
  float qr = ws[WS_QY + 3200 + d];
  float mr = 0.f;
#pragma unroll 8
  for (int c = 0; c < 64; c++) mr += s_cs[c] * dw[d * 64 + c];
  mr *= (1.0f / 409600.0f);
  float varr = qr * (1.0f / 409600.0f) - mr * mr;
  float ar = dgamma[d] * rsqrtf(varr + EPSF);
  float br = dbeta[d] - mr * ar;
  float4 c4 = make_float4(ay, by + br, ar, 0.f);
#pragma unroll
  for (int r = 0; r < 4; r++)
    ((float4*)(ws + WS_CFL))[d * 100 + r * 25 + vo] = c4;
}

// ---------------- reduce (fallback path): ABY/ABR for k_main ----------------
__global__ void k_reduce_f(const float* __restrict__ gamma, const float* __restrict__ beta,
                           const float* __restrict__ dgamma, const float* __restrict__ dbeta,
                           const float* __restrict__ W, const float* __restrict__ dw,
                           float* __restrict__ ws) {
  int tid = threadIdx.x;
  if (blockIdx.x == 25) {
    __shared__ float s_cs[64];
    if (tid < 64) {
      float s = 0.f;
#pragma unroll
      for (int v = 0; v < 25; v++) s += ws[WS_COLSUM + v * 64 + tid];
      s_cs[tid] = s;
    }
    __syncthreads();
    if (tid >= 128) return;
    int d = tid;
    float q = ws[WS_QY + 3200 + d];
    float m = 0.f;
#pragma unroll 8
    for (int c = 0; c < 64; c++) m += s_cs[c] * dw[d * 64 + c];
    m *= (1.0f / 409600.0f);
    float var = q * (1.0f / 409600.0f) - m * m;
    float a = dgamma[d] * rsqrtf(var + EPSF);
    ((float2*)(ws + WS_ABR))[d] = make_float2(a, dbeta[d] - m * a);
    return;
  }
  __shared__ float s_cm[1600];
  for (int t = tid; t < 1600; t += 128)
    s_cm[t] = ws[WS_COLSUM + t] * ws[WS_MASKJ + t];
  __syncthreads();
  int f = blockIdx.x * 128 + tid;
  int v = f >> 7, d = f & 127;
  float q = ws[WS_QY + f];
  float m = 0.f;
  int p = v * 64;
#pragma unroll 8
  for (int c = 0; c < 64; c++) {
    m += s_cm[p] * W[c * 128 + d];
    p += 65; if (p >= VC) p -= VC;
  }
  m *= (1.0f / 16384.0f);
  float var = q * (1.0f / 16384.0f) - m * m;
  int d25 = d % 25;
  int vo = v + d25; if (vo >= 25) vo -= 25;
  int jg = vo * 128 + d;
  float a = gamma[jg] * rsqrtf(var + EPSF);
  ((float2*)(ws + WS_ABY))[f] = make_float2(a, beta[jg] - m * a);
}

// ---------------- pass 2 (big path): pure streamer, no LDS ----------------
__global__ void k_out(const float* __restrict__ ws, float* __restrict__ out) {
  int tid = threadIdx.x, cg = blockIdx.x;
  const short* gyr = (const short*)ws + WS_YR_SH + (size_t)cg * 25600;
  const float4* cfl = (const float4*)(ws + WS_CFL);
  int n0 = cg * 4;
  int b = n0 >> 9, t0 = n0 & 511;
  float* ob = out + (size_t)b * 1638400 + (size_t)t0 * 25;
  for (int t = tid; t < 3200; t += 256) {
    s16x8 w = *(const s16x8*)(gyr + t * 8);   // 4 (y,r) pairs, linear
    float ov[4];
#pragma unroll
    for (int j = 0; j < 4; j++) {
      float4 c4 = cfl[t * 4 + j];
      ov[j] = fmaxf(bf2f(w[2 * j]) * c4.x + bf2f(w[2 * j + 1]) * c4.z + c4.y, 0.0f);
    }
    int d = t / 25;
    int L0 = (t - d * 25) * 4;
    float4 o; o.x = ov[0]; o.y = ov[1]; o.z = ov[2]; o.w = ov[3];
    *(float4*)(ob + (size_t)d * 12800 + L0) = o;
  }
}

// ---------------- fallback pass 2 (small ws): original recompute kernel ----------------
__launch_bounds__(256, 2)
__global__ void k_main(const float* __restrict__ x0, const float* __restrict__ ws,
                       float* __restrict__ out) {
  __shared__ short s_raw[112 * 72];
  __shared__ short s_xm[112 * 72];
  __shared__ short s_ybuf[100 * 129];
  int tid = threadIdx.x;
  int wave = tid >> 6, lane = tid & 63, quad = lane >> 4, l15 = lane & 15;
  int n0 = blockIdx.x * 4;
  for (int t = tid; t < 1600; t += 256) {
    int flat = t * 4;
    int nl = flat / VC;
    int j = flat - nl * VC;
    float4 xv = *(const float4*)(x0 + (size_t)n0 * VC + flat);
    float4 m4 = *(const float4*)(ws + WS_MASKJ + j);
    float mj[4] = {m4.x, m4.y, m4.z, m4.w};
    stage_elem(j, nl * 25, 1, xv, mj, (short*)s_raw, (short*)s_xm);
  }
  __syncthreads();
  const s16x8* wpack = (const s16x8*)(ws + WS_WPACK);
  const float2* aby = (const float2*)(ws + WS_ABY);
  {
    s16x8 b0, b1;
#pragma unroll
    for (int ji = 0; ji < 14; ji++) {
      int job = wave * 14 + ji;
      int nt = job / 7, mt = job - nt * 7;
      if (ji == 0 || ji == 7) {
        b0 = wpack[(nt * 2 + 0) * 64 + lane];
        b1 = wpack[(nt * 2 + 1) * 64 + lane];
      }
      int mbase = mt * 16;
      const short* pa = s_xm + (mbase + l15) * 72 + quad * 8;
      s16x8 a0 = *(const s16x8*)(pa);
      s16x8 a1 = *(const s16x8*)(pa + 32);
      f32x4 acc = {0.f, 0.f, 0.f, 0.f};
      acc = __builtin_amdgcn_mfma_f32_16x16x32_bf16(a0, b0, acc, 0, 0, 0);
      acc = __builtin_amdgcn_mfma_f32_16x16x32_bf16(a1, b1, acc, 0, 0, 0);
      int d = nt * 16 + l15;
      int d25 = d % 25;
#pragma unroll
      for (int i = 0; i < 4; i++) {
        int s = mbase + quad * 4 + i;
        if (s < 100) {
          int r = s / 25;
          int vv = s - r * 25;
          float2 ab = aby[vv * 128 + d];
          float val = acc[i] * ab.x + ab.y;
          int vo = vv + d25; if (vo >= 25) vo -= 25;
          s_ybuf[(r * 25 + vo) * 129 + d] = f2bf(val);
        }
      }
    }
  }
  __syncthreads();
  const s16x8* dwpack = (const s16x8*)(ws + WS_DWPACK);
  const float2* abr = (const float2*)(ws + WS_ABR);
  {
    s16x8 b0, b1; float2 ab = make_float2(0.f, 0.f);
#pragma unroll
    for (int ji = 0; ji < 14; ji++) {
      int job = wave * 14 + ji;
      int nt = job / 7, mt = job - nt * 7;
      if (ji == 0 || ji == 7) {
        b0 = dwpack[(nt * 2 + 0) * 64 + lane];
        b1 = dwpack[(nt * 2 + 1) * 64 + lane];
        ab = abr[nt * 16 + l15];
      }
      int mbase = mt * 16;
      const short* pa = s_raw + (mbase + l15) * 72 + quad * 8;
      s16x8 a0 = *(const s16x8*)(pa);
      s16x8 a1 = *(const s16x8*)(pa + 32);
      f32x4 acc = {0.f, 0.f, 0.f, 0.f};
      acc = __builtin_amdgcn_mfma_f32_16x16x32_bf16(a0, b0, acc, 0, 0, 0);
      acc = __builtin_amdgcn_mfma_f32_16x16x32_bf16(a1, b1, acc, 0, 0, 0);
      int d = nt * 16 + l15;
#pragma unroll
      for (int i = 0; i < 4; i++) {
        int s = mbase + quad * 4 + i;
        if (s < 100) {
          int r = s / 25;
          int vv = s - r * 25;
          int ad = (r * 25 + vv) * 129 + d;
          float val = acc[i] * ab.x + ab.y + bf2f(s_ybuf[ad]);
          val = fmaxf(val, 0.0f);
          s_ybuf[ad] = f2bf(val);
        }
      }
    }
  }
  __syncthreads();
  int b = n0 >> 9, t0 = n0 & 511;
  float* ob = out + (size_t)b * 1638400 + (size_t)t0 * 25;
  for (int it = tid; it < 3200; it += 256) {
    int dd = it / 25;
    int qg = it - dd * 25;
    int q0 = qg * 4;
    float4 o;
    o.x = bf2f(s_ybuf[(q0 + 0) * 129 + dd]);
    o.y = bf2f(s_ybuf[(q0 + 1) * 129 + dd]);
    o.z = bf2f(s_ybuf[(q0 + 2) * 129 + dd]);
    o.w = bf2f(s_ybuf[(q0 + 3) * 129 + dd]);
    *(float4*)(ob + (size_t)dd * 12800 + q0) = o;
  }
}

extern "C" void kernel_launch(void* const* d_in, const int* in_sizes, int n_in,
                              void* d_out, int out_size, void* d_ws, size_t ws_size,
                              hipStream_t stream) {
  const float* x0    = (const float*)d_in[0];
  const float* fm    = (const float*)d_in[1];
  const float* W     = (const float*)d_in[2];
  const float* bn_g  = (const float*)d_in[4];
  const float* bn_b  = (const float*)d_in[5];
  const float* dw    = (const float*)d_in[6];
  const float* dbn_g = (const float*)d_in[8];
  const float* dbn_b = (const float*)d_in[9];
  float* ws = (float*)d_ws;
  float* out = (float*)d_out;
  int big = (ws_size >= WS_NEED_BYTES) ? 1 : 0;
  k_init<<<21, 256, 0, stream>>>(fm, W, dw, ws);
  k_stats<<<512, 256, 0, stream>>>(x0, ws, big);
  if (big) {
    k_reduce_big<<<25, 128, 0, stream>>>(bn_g, bn_b, dbn_g, dbn_b, W, dw, ws);
    k_out<<<4096, 256, 0, stream>>>(ws, out);
  } else {
    k_reduce_f<<<26, 128, 0, stream>>>(bn_g, bn_b, dbn_g, dbn_b, W, dw, ws);
    k_main<<<4096, 256, 0, stream>>>(x0, ws, out);
  }
}

// Round 6
// 688.571 us; speedup vs baseline: 1.1419x; 1.1419x over previous
//
#include <hip/hip_runtime.h>

#define VC 1600
#define EPSF 1e-5f

// ws layout (float offsets)
#define WS_MASKJ  0
#define WS_WPACK  1600
#define WS_DWPACK 5696
#define WS_ABY    9792             // fallback path
#define WS_ABR    16192            // fallback path
#define WS_COLSUM 16448
#define WS_QY     18048            // 3328 floats: [0,3200)=y (v,d) sumsq, [3200,3328)=res d sumsq
#define WS_CFL    24576            // float4[3200]: fused coeffs (ay, by+br, ar, 0) indexed d*25+vo
#define WS_YR_SH  153600           // SHORT offset: interleaved (y,r) bf16, [cg][d][L][2], 12800/chunk
#define WS_NEED_BYTES 216628736ULL

typedef __attribute__((ext_vector_type(8))) short s16x8;
typedef __attribute__((ext_vector_type(4))) short s16x4;
typedef __attribute__((ext_vector_type(4))) float f32x4;

__device__ __forceinline__ short f2bf(float f) {
  unsigned u = __builtin_bit_cast(unsigned, f);
  u += 0x7fffu + ((u >> 16) & 1u);
  return (short)(u >> 16);
}
__device__ __forceinline__ float bf2f(short s) {
  unsigned u = ((unsigned)(unsigned short)s) << 16;
  return __builtin_bit_cast(float, u);
}

// stage one float4: raw (contiguous) + masked scatter to gathered position.
// raw slot = base + u*vstr ; gathered slot = base + v(j)*vstr
__device__ __forceinline__ void stage_elem(int j, int base, int vstr, float4 xv,
                                           const float* mj, short* s_raw, short* s_xm) {
  int u = j >> 6, c = j & 63;
  s16x4 pk; pk[0]=f2bf(xv.x); pk[1]=f2bf(xv.y); pk[2]=f2bf(xv.z); pk[3]=f2bf(xv.w);
  *(s16x4*)(s_raw + (base + u*vstr)*72 + c) = pk;
  int v0 = (u - c + 75) % 25;
  float xa[4] = {xv.x, xv.y, xv.z, xv.w};
#pragma unroll
  for (int e = 0; e < 4; e++) {
    int ve = v0 - e; if (ve < 0) ve += 25;
    s_xm[(base + ve*vstr)*72 + c + e] = f2bf(xa[e] * mj[e]);
  }
}

// ---------------- init ----------------
__global__ void k_init(const float* __restrict__ fm, const float* __restrict__ W,
                       const float* __restrict__ dw, float* __restrict__ ws) {
  int g = blockIdx.x * 256 + threadIdx.x;
  if (g < VC) {
    int c = g & 63, jv = g >> 6;
    int v = (jv - c + 75) % 25;
    ws[WS_MASKJ + g] = tanhf(fm[v * 64 + c]) + 1.0f;
    ws[WS_COLSUM + g] = 0.0f;
  }
  if (g < 3328) ws[WS_QY + g] = 0.0f;
  if (g >= 3328 && g < 4352) {
    int idx = g - 3328;
    int frag = idx >> 6, lane = idx & 63;
    int nt = frag >> 1, k = frag & 1, q = lane >> 4, l = lane & 15;
    s16x8 pk;
#pragma unroll
    for (int j = 0; j < 8; j++) {
      int c = k * 32 + q * 8 + j;
      pk[j] = f2bf(W[c * 128 + nt * 16 + l]);
    }
    ((s16x8*)(ws + WS_WPACK))[idx] = pk;
  }
  if (g >= 4352 && g < 5376) {
    int idx = g - 4352;
    int frag = idx >> 6, lane = idx & 63;
    int nt = frag >> 1, k = frag & 1, q = lane >> 4, l = lane & 15;
    s16x8 pk;
#pragma unroll
    for (int j = 0; j < 8; j++) {
      int c = k * 32 + q * 8 + j;
      pk[j] = f2bf(dw[(nt * 16 + l) * 64 + c]);
    }
    ((s16x8*)(ws + WS_DWPACK))[idx] = pk;
  }
}

// ---------------- pass 1: 2-row chunks, normal-orientation MFMA, in-loop LDS scatter ----------------
// slot = r + 2*v (r in 0..1, v in 0..24) -> slots 0..49 valid, 50..63 zero pad.
// 4 MFMA tiles of 16 slots. Lane owns (quad,i): slot = vp*16+quad*4+i, v = slot>>1 (2 v's/lane/tile).
// Scatter acc -> s_yr[d][L=r*25+vo][2] immediately (no cross-barrier regs). Flush linear.
__launch_bounds__(256, 3)
__global__ void k_stats(const float* __restrict__ x0, float* __restrict__ ws, int do_store) {
  __shared__ __align__(16) short s_raw[4608];   // 64 slots x 72
  __shared__ __align__(16) short s_xm[4608];
  __shared__ __align__(16) short s_yr[12800];   // [d=128][L=50][2]
  int tid = threadIdx.x;
  int wave = tid >> 6, lane = tid & 63, quad = lane >> 4, l15 = lane & 15;
  // zero pad slots 50..63 once (never rewritten)
  for (int t = tid; t < 1008; t += 256) { s_raw[3600 + t] = 0; s_xm[3600 + t] = 0; }
  const s16x8* wpack = (const s16x8*)(ws + WS_WPACK);
  const s16x8* dwpack = (const s16x8*)(ws + WS_DWPACK);

  int nt0 = wave * 2;
  s16x8 bw[2][2], bd[2][2];
#pragma unroll
  for (int a = 0; a < 2; a++) {
    int nt = nt0 + a;
    bw[a][0] = wpack[(nt * 2 + 0) * 64 + lane];
    bw[a][1] = wpack[(nt * 2 + 1) * 64 + lane];
    bd[a][0] = dwpack[(nt * 2 + 0) * 64 + lane];
    bd[a][1] = dwpack[(nt * 2 + 1) * 64 + lane];
  }
  int d25a[2];
  d25a[0] = (nt0 * 16 + l15) % 25;
  d25a[1] = ((nt0 + 1) * 16 + l15) % 25;
  float mj0[4], mj1[4];
  {
    float4 m4 = *(const float4*)(ws + WS_MASKJ + tid * 4);
    mj0[0]=m4.x; mj0[1]=m4.y; mj0[2]=m4.z; mj0[3]=m4.w;
  }
  if (tid < 144) {
    float4 m4 = *(const float4*)(ws + WS_MASKJ + 1024 + tid * 4);
    mj1[0]=m4.x; mj1[1]=m4.y; mj1[2]=m4.z; mj1[3]=m4.w;
  }
  float cs[8] = {0,0,0,0,0,0,0,0};
  float rq0 = 0.f, rq1 = 0.f;
  float qy[4][2][2];
#pragma unroll
  for (int i = 0; i < 4; i++)
#pragma unroll
    for (int h = 0; h < 2; h++) { qy[i][h][0] = 0.f; qy[i][h][1] = 0.f; }

  for (int chunk = 0; chunk < 16; chunk++) {
    int n0 = blockIdx.x * 32 + chunk * 2;
    int cg = blockIdx.x * 16 + chunk;
    __syncthreads();   // prev MFMA reads + prev flush reads done
    for (int r = 0; r < 2; r++) {
      const float* rowp = x0 + (size_t)(n0 + r) * VC;
      float4 xv = *(const float4*)(rowp + tid * 4);
      cs[0]+=xv.x; cs[1]+=xv.y; cs[2]+=xv.z; cs[3]+=xv.w;
      stage_elem(tid * 4, r, 2, xv, mj0, s_raw, s_xm);
      if (tid < 144) {
        float4 xw = *(const float4*)(rowp + 1024 + tid * 4);
        cs[4]+=xw.x; cs[5]+=xw.y; cs[6]+=xw.z; cs[7]+=xw.w;
        stage_elem(1024 + tid * 4, r, 2, xw, mj1, s_raw, s_xm);
      }
    }
    __syncthreads();
#pragma unroll
    for (int vp = 0; vp < 4; vp++) {
      int rb = vp * 16;
      const short* px = s_xm + (rb + l15) * 72 + quad * 8;
      const short* pr = s_raw + (rb + l15) * 72 + quad * 8;
      s16x8 a0 = *(const s16x8*)px;
      s16x8 a1 = *(const s16x8*)(px + 32);
      s16x8 r0 = *(const s16x8*)pr;
      s16x8 r1 = *(const s16x8*)(pr + 32);
#pragma unroll
      for (int a = 0; a < 2; a++) {
        f32x4 acc = {0.f, 0.f, 0.f, 0.f};
        acc = __builtin_amdgcn_mfma_f32_16x16x32_bf16(a0, bw[a][0], acc, 0, 0, 0);
        acc = __builtin_amdgcn_mfma_f32_16x16x32_bf16(a1, bw[a][1], acc, 0, 0, 0);
        f32x4 rc = {0.f, 0.f, 0.f, 0.f};
        rc = __builtin_amdgcn_mfma_f32_16x16x32_bf16(r0, bd[a][0], rc, 0, 0, 0);
        rc = __builtin_amdgcn_mfma_f32_16x16x32_bf16(r1, bd[a][1], rc, 0, 0, 0);
        int d = (nt0 + a) * 16 + l15;
#pragma unroll
        for (int i = 0; i < 4; i++) {
          // stats: pad slots are zero -> contribute 0, no guard needed
          qy[vp][i >> 1][a] += acc[i] * acc[i];
          if (a == 0) rq0 += rc[i] * rc[i]; else rq1 += rc[i] * rc[i];
          if (do_store) {
            int slot = rb + quad * 4 + i;
            if (vp < 3 || slot < 50) {   // compile-time true for vp<3
              int v = slot >> 1, r = slot & 1;
              int vo = v + d25a[a]; if (vo >= 25) vo -= 25;
              s_yr[(d * 50 + r * 25 + vo) * 2]     = f2bf(acc[i]);  // y shifted
              s_yr[(d * 50 + r * 25 + v) * 2 + 1]  = f2bf(rc[i]);   // res unshifted
            }
          }
        }
      }
    }
    __syncthreads();   // scatter done before flush reads
    if (do_store) {
      short* gyr = (short*)ws + WS_YR_SH + (size_t)cg * 12800;
      for (int t = tid; t < 1600; t += 256)
        *(s16x8*)(gyr + t * 8) = *(const s16x8*)(s_yr + t * 8);
    }
  }
  // accumulate stats straight into global accumulators (zeroed by k_init each launch)
  rq0 += __shfl_xor(rq0, 16); rq0 += __shfl_xor(rq0, 32);
  rq1 += __shfl_xor(rq1, 16); rq1 += __shfl_xor(rq1, 32);
  if (quad == 0) {
    atomicAdd(ws + WS_QY + 3200 + nt0 * 16 + l15, rq0);
    atomicAdd(ws + WS_QY + 3200 + (nt0 + 1) * 16 + l15, rq1);
  }
#pragma unroll
  for (int vp = 0; vp < 4; vp++)
#pragma unroll
    for (int h = 0; h < 2; h++) {
      int v = vp * 8 + quad * 2 + h;
      if (v < 25) {
        atomicAdd(ws + WS_QY + v * 128 + nt0 * 16 + l15, qy[vp][h][0]);
        atomicAdd(ws + WS_QY + v * 128 + (nt0 + 1) * 16 + l15, qy[vp][h][1]);
      }
    }
#pragma unroll
  for (int e = 0; e < 4; e++) atomicAdd(ws + WS_COLSUM + tid * 4 + e, cs[e]);
  if (tid < 144) {
#pragma unroll
    for (int e = 0; e < 4; e++) atomicAdd(ws + WS_COLSUM + 1024 + tid * 4 + e, cs[4 + e]);
  }
}

// ---------------- reduce (big path): fused coeff table CFL[d*25+vo] ----------------
__global__ void k_reduce_big(const float* __restrict__ gamma, const float* __restrict__ beta,
                             const float* __restrict__ dgamma, const float* __restrict__ dbeta,
                             const float* __restrict__ W, const float* __restrict__ dw,
                             float* __restrict__ ws) {
  __shared__ float s_cm[1600];
  __shared__ float s_cs[64];
  int tid = threadIdx.x;
  for (int t = tid; t < 1600; t += 128) s_cm[t] = ws[WS_COLSUM + t] * ws[WS_MASKJ + t];
  if (tid < 64) {
    float s = 0.f;
#pragma unroll
    for (int v2 = 0; v2 < 25; v2++) s += ws[WS_COLSUM + v2 * 64 + tid];
    s_cs[tid] = s;
  }
  __syncthreads();
  int v = blockIdx.x, d = tid;
  float q = ws[WS_QY + v * 128 + d];
  float m = 0.f;
  int p = v * 64;
#pragma unroll 8
  for (int c = 0; c < 64; c++) { m += s_cm[p] * W[c * 128 + d]; p += 65; if (p >= VC) p -= VC; }
  m *= (1.0f / 16384.0f);
  float var = q * (1.0f / 16384.0f) - m * m;
  int d25 = d % 25;
  int vo = v + d25; if (vo >= 25) vo -= 25;
  int jg = vo * 128 + d;
  float ay = gamma[jg] * rsqrtf(var + EPSF);
  float by = beta[jg] - m * ay;
  float qr = ws[WS_QY + 3200 + d];
  float mr = 0.f;
#pragma unroll 8
  for (int c = 0; c < 64; c++) mr += s_cs[c] * dw[d * 64 + c];
  mr *= (1.0f / 409600.0f);
  float varr = qr * (1.0f / 409600.0f) - mr * mr;
  float ar = dgamma[d] * rsqrtf(varr + EPSF);
  float br = dbeta[d] - mr * ar;
  ((float4*)(ws + WS_CFL))[d * 25 + vo] = make_float4(ay, by + br, ar, 0.f);
}

// ---------------- reduce (fallback path): ABY/ABR for k_main ----------------
__global__ void k_reduce_f(const float* __restrict__ gamma, const float* __restrict__ beta,
                           const float* __restrict__ dgamma, const float* __restrict__ dbeta,
                           const float* __restrict__ W, const float* __restrict__ dw,
                           float* __restrict__ ws) {
  int tid = threadIdx.x;
  if (blockIdx.x == 25) {
    __shared__ float s_cs[64];
    if (tid < 64) {
      float s = 0.f;
#pragma unroll
      for (int v = 0; v < 25; v++) s += ws[WS_COLSUM + v * 64 + tid];
      s_cs[tid] = s;
    }
    __syncthreads();
    if (tid >= 128) return;
    int d = tid;
    float q = ws[WS_QY + 3200 + d];
    float m = 0.f;
#pragma unroll 8
    for (int c = 0; c < 64; c++) m += s_cs[c] * dw[d * 64 + c];
    m *= (1.0f / 409600.0f);
    float var = q * (1.0f / 409600.0f) - m * m;
    float a = dgamma[d] * rsqrtf(var + EPSF);
    ((float2*)(ws + WS_ABR))[d] = make_float2(a, dbeta[d] - m * a);
    return;
  }
  __shared__ float s_cm[1600];
  for (int t = tid; t < 1600; t += 128)
    s_cm[t] = ws[WS_COLSUM + t] * ws[WS_MASKJ + t];
  __syncthreads();
  int f = blockIdx.x * 128 + tid;
  int v = f >> 7, d = f & 127;
  float q = ws[WS_QY + f];
  float m = 0.f;
  int p = v * 64;
#pragma unroll 8
  for (int c = 0; c < 64; c++) {
    m += s_cm[p] * W[c * 128 + d];
    p += 65; if (p >= VC) p -= VC;
  }
  m *= (1.0f / 16384.0f);
  float var = q * (1.0f / 16384.0f) - m * m;
  int d25 = d % 25;
  int vo = v + d25; if (vo >= 25) vo -= 25;
  int jg = vo * 128 + d;
  float a = gamma[jg] * rsqrtf(var + EPSF);
  ((float2*)(ws + WS_ABY))[f] = make_float2(a, beta[jg] - m * a);
}

// ---------------- pass 2 (big path): pure streamer, no LDS ----------------
__global__ void k_out(const float* __restrict__ ws, float* __restrict__ out) {
  int tid = threadIdx.x, cg = blockIdx.x;
  const short* gyr = (const short*)ws + WS_YR_SH + (size_t)cg * 12800;
  const float4* cfl = (const float4*)(ws + WS_CFL);
  int n0 = cg * 2;
  int b = n0 >> 9, t0 = n0 & 511;
  float* ob = out + (size_t)b * 1638400 + (size_t)t0 * 25;
  for (int t = tid; t < 3200; t += 256) {
    s16x4 w = *(const s16x4*)(gyr + t * 4);   // pairs (y0,r0,y1,r1), linear
    int d = t / 25;
    int L0 = (t - d * 25) * 2;
    int vo0 = (L0 >= 25) ? L0 - 25 : L0;
    int L1 = L0 + 1;
    int vo1 = (L1 >= 25) ? L1 - 25 : L1;
    float4 c0 = cfl[d * 25 + vo0];
    float4 c1 = cfl[d * 25 + vo1];
    float o0 = fmaxf(bf2f(w[0]) * c0.x + bf2f(w[1]) * c0.z + c0.y, 0.0f);
    float o1 = fmaxf(bf2f(w[2]) * c1.x + bf2f(w[3]) * c1.z + c1.y, 0.0f);
    *(float2*)(ob + (size_t)d * 12800 + L0) = make_float2(o0, o1);
  }
}

// ---------------- fallback pass 2 (small ws): original recompute kernel ----------------
__launch_bounds__(256, 2)
__global__ void k_main(const float* __restrict__ x0, const float* __restrict__ ws,
                       float* __restrict__ out) {
  __shared__ short s_raw[112 * 72];
  __shared__ short s_xm[112 * 72];
  __shared__ short s_ybuf[100 * 129];
  int tid = threadIdx.x;
  int wave = tid >> 6, lane = tid & 63, quad = lane >> 4, l15 = lane & 15;
  int n0 = blockIdx.x * 4;
  for (int t = tid; t < 1600; t += 256) {
    int flat = t * 4;
    int nl = flat / VC;
    int j = flat - nl * VC;
    float4 xv = *(const float4*)(x0 + (size_t)n0 * VC + flat);
    float4 m4 = *(const float4*)(ws + WS_MASKJ + j);
    float mj[4] = {m4.x, m4.y, m4.z, m4.w};
    stage_elem(j, nl * 25, 1, xv, mj, (short*)s_raw, (short*)s_xm);
  }
  __syncthreads();
  const s16x8* wpack = (const s16x8*)(ws + WS_WPACK);
  const float2* aby = (const float2*)(ws + WS_ABY);
  {
    s16x8 b0, b1;
#pragma unroll
    for (int ji = 0; ji < 14; ji++) {
      int job = wave * 14 + ji;
      int nt = job / 7, mt = job - nt * 7;
      if (ji == 0 || ji == 7) {
        b0 = wpack[(nt * 2 + 0) * 64 + lane];
        b1 = wpack[(nt * 2 + 1) * 64 + lane];
      }
      int mbase = mt * 16;
      const short* pa = s_xm + (mbase + l15) * 72 + quad * 8;
      s16x8 a0 = *(const s16x8*)(pa);
      s16x8 a1 = *(const s16x8*)(pa + 32);
      f32x4 acc = {0.f, 0.f, 0.f, 0.f};
      acc = __builtin_amdgcn_mfma_f32_16x16x32_bf16(a0, b0, acc, 0, 0, 0);
      acc = __builtin_amdgcn_mfma_f32_16x16x32_bf16(a1, b1, acc, 0, 0, 0);
      int d = nt * 16 + l15;
      int d25 = d % 25;
#pragma unroll
      for (int i = 0; i < 4; i++) {
        int s = mbase + quad * 4 + i;
        if (s < 100) {
          int r = s / 25;
          int vv = s - r * 25;
          float2 ab = aby[vv * 128 + d];
          float val = acc[i] * ab.x + ab.y;
          int vo = vv + d25; if (vo >= 25) vo -= 25;
          s_ybuf[(r * 25 + vo) * 129 + d] = f2bf(val);
        }
      }
    }
  }
  __syncthreads();
  const s16x8* dwpack = (const s16x8*)(ws + WS_DWPACK);
  const float2* abr = (const float2*)(ws + WS_ABR);
  {
    s16x8 b0, b1; float2 ab = make_float2(0.f, 0.f);
#pragma unroll
    for (int ji = 0; ji < 14; ji++) {
      int job = wave * 14 + ji;
      int nt = job / 7, mt = job - nt * 7;
      if (ji == 0 || ji == 7) {
        b0 = dwpack[(nt * 2 + 0) * 64 + lane];
        b1 = dwpack[(nt * 2 + 1) * 64 + lane];
        ab = abr[nt * 16 + l15];
      }
      int mbase = mt * 16;
      const short* pa = s_raw + (mbase + l15) * 72 + quad * 8;
      s16x8 a0 = *(const s16x8*)(pa);
      s16x8 a1 = *(const s16x8*)(pa + 32);
      f32x4 acc = {0.f, 0.f, 0.f, 0.f};
      acc = __builtin_amdgcn_mfma_f32_16x16x32_bf16(a0, b0, acc, 0, 0, 0);
      acc = __builtin_amdgcn_mfma_f32_16x16x32_bf16(a1, b1, acc, 0, 0, 0);
      int d = nt * 16 + l15;
#pragma unroll
      for (int i = 0; i < 4; i++) {
        int s = mbase + quad * 4 + i;
        if (s < 100) {
          int r = s / 25;
          int vv = s - r * 25;
          int ad = (r * 25 + vv) * 129 + d;
          float val = acc[i] * ab.x + ab.y + bf2f(s_ybuf[ad]);
          val = fmaxf(val, 0.0f);
          s_ybuf[ad] = f2bf(val);
        }
      }
    }
  }
  __syncthreads();
  int b = n0 >> 9, t0 = n0 & 511;
  float* ob = out + (size_t)b * 1638400 + (size_t)t0 * 25;
  for (int it = tid; it < 3200; it += 256) {
    int dd = it / 25;
    int qg = it - dd * 25;
    int q0 = qg * 4;
    float4 o;
    o.x = bf2f(s_ybuf[(q0 + 0) * 129 + dd]);
    o.y = bf2f(s_ybuf[(q0 + 1) * 129 + dd]);
    o.z = bf2f(s_ybuf[(q0 + 2) * 129 + dd]);
    o.w = bf2f(s_ybuf[(q0 + 3) * 129 + dd]);
    *(float4*)(ob + (size_t)dd * 12800 + q0) = o;
  }
}

extern "C" void kernel_launch(void* const* d_in, const int* in_sizes, int n_in,
                              void* d_out, int out_size, void* d_ws, size_t ws_size,
                              hipStream_t stream) {
  const float* x0    = (const float*)d_in[0];
  const float* fm    = (const float*)d_in[1];
  const float* W     = (const float*)d_in[2];
  const float* bn_g  = (const float*)d_in[4];
  const float* bn_b  = (const float*)d_in[5];
  const float* dw    = (const float*)d_in[6];
  const float* dbn_g = (const float*)d_in[8];
  const float* dbn_b = (const float*)d_in[9];
  float* ws = (float*)d_ws;
  float* out = (float*)d_out;
  int big = (ws_size >= WS_NEED_BYTES) ? 1 : 0;
  k_init<<<21, 256, 0, stream>>>(fm, W, dw, ws);
  k_stats<<<512, 256, 0, stream>>>(x0, ws, big);
  if (big) {
    k_reduce_big<<<25, 128, 0, stream>>>(bn_g, bn_b, dbn_g, dbn_b, W, dw, ws);
    k_out<<<8192, 256, 0, stream>>>(ws, out);
  } else {
    k_reduce_f<<<26, 128, 0, stream>>>(bn_g, bn_b, dbn_g, dbn_b, W, dw, ws);
    k_main<<<4096, 256, 0, stream>>>(x0, ws, out);
  }
}